// Round 6
// baseline (92.715 us; speedup 1.0000x reference)
//
#include <hip/hip_runtime.h>
#include <hip/hip_bf16.h>

// Problem constants (from reference)
#define NN0   292864
#define NN1   11264
#define BB    1024
#define FF0   256
#define FF1   256
#define CC    47
#define FAN0  25
#define FAN1  10

typedef __bf16 bf16x8 __attribute__((ext_vector_type(8)));
typedef float  f32x4  __attribute__((ext_vector_type(4)));

static __device__ __forceinline__ unsigned short f2bf(float f) {
    unsigned int u = __float_as_uint(f);
    u = u + 0x7fffu + ((u >> 16) & 1u);   // round-to-nearest-even
    return (unsigned short)(u >> 16);
}
static __device__ __forceinline__ float bf2f(unsigned short u) {
    return __uint_as_float(((unsigned int)u) << 16);
}

// ---------------------------------------------------------------------------
// Kernel 1 (round-3 form, verbatim): per-node mean of 25 gathered x-rows +
// self-row -> bf16. 1 wave per node, lane = one float4.
// ---------------------------------------------------------------------------
__global__ __launch_bounds__(256) void k_gather0(
    const float* __restrict__ x, const int* __restrict__ src0,
    unsigned short* __restrict__ A)
{
    const int wave = threadIdx.x >> 6;
    const int lane = threadIdx.x & 63;
    const int node = (blockIdx.x << 2) + wave;   // grid 2816 * 4 = 11264 exact
    const float4* __restrict__ x4 = (const float4*)x;

    float4 s = x4[(size_t)node * 64 + lane];

    float ax = 0.f, ay = 0.f, az = 0.f, aw = 0.f;
    const int* sp = src0 + node * FAN0;
    #pragma unroll 5
    for (int e = 0; e < FAN0; ++e) {
        float4 v = x4[(size_t)sp[e] * 64 + lane];
        ax += v.x; ay += v.y; az += v.z; aw += v.w;
    }
    const float inv = 1.0f / (float)FAN0;

    ushort4 selfp, meanp;
    selfp.x = f2bf(s.x); selfp.y = f2bf(s.y); selfp.z = f2bf(s.z); selfp.w = f2bf(s.w);
    meanp.x = f2bf(ax * inv); meanp.y = f2bf(ay * inv);
    meanp.z = f2bf(az * inv); meanp.w = f2bf(aw * inv);

    const size_t base = (size_t)node * 512 + lane * 4;
    *(ushort4*)(&A[base])       = selfp;
    *(ushort4*)(&A[base + 256]) = meanp;
}

// ---------------------------------------------------------------------------
// Kernel 2 (unchanged): weight transpose+concat
// Wt[n][k] = bf16( k<256 ? Ws0[k][n] : Wn0[k-256][n] )
// ---------------------------------------------------------------------------
__global__ __launch_bounds__(256) void k_wconv(
    const float* __restrict__ Ws0, const float* __restrict__ Wn0,
    unsigned short* __restrict__ Wt)
{
    const int n = blockIdx.x;
    for (int k = threadIdx.x; k < 512; k += 256) {
        float v = (k < 256) ? Ws0[k * 256 + n] : Wn0[(k - 256) * 256 + n];
        Wt[n * 512 + k] = f2bf(v);
    }
}

// ---------------------------------------------------------------------------
// Kernel 3 (ONLY change this round): h = relu(A @ Wt^T + b0) -> bf16
// M=11264 N=256 K=512. Tile 128x64, BK=64 -> 8 K-tiles, 16 barriers (was 32).
// Linear LDS (no pad) with XOR chunk swizzle (T2, reg-staged both sides):
//   data chunk (row, c) lives at slot c ^ (row&7); applied on ds_write AND
//   ds_read. Read conflicts: lanes 0-15 -> 8 distinct 16B slots, rows r/r+8
//   alias 2-way = free (m136). 24 KB LDS.
// Per K-tile: 6 global uint4 loads/thread (prefetched under MFMAs),
// 12 ds_read_b128 + 16 MFMA per wave.
// ---------------------------------------------------------------------------
__global__ __launch_bounds__(256) void k_gemm0(
    const unsigned short* __restrict__ A,   // [11264][512] bf16 bits
    const unsigned short* __restrict__ Wt,  // [256][512]   bf16 bits
    const float* __restrict__ b0,
    unsigned short* __restrict__ h)         // [11264][256] bf16 bits
{
    __shared__ unsigned short As[128 * 64];   // 16 KB
    __shared__ unsigned short Bs[64 * 64];    //  8 KB

    const int t     = threadIdx.x;
    const int mBase = blockIdx.x * 128;
    const int nBase = blockIdx.y * 64;
    const int lane  = t & 63;
    const int wave  = t >> 6;
    const int wm    = wave >> 1;     // 0..1 : which 64-row half
    const int wn    = wave & 1;      // 0..1 : which 32-col half
    const int rl    = lane & 15;
    const int qk    = lane >> 4;     // 0..3 : k-quarter of the 64-wide window

    // staging decomposition: chunk id -> row = id>>3, c = id&7 (8 chunks/row)
    // A: 1024 chunks (ids t+i*256, i=0..3); B: 512 chunks (ids t+i*256, i=0..1)
    int arow[4], ac[4], brow[2], bc[2];
    int aslot[4], bslot[2];          // swizzled LDS short-offsets
    #pragma unroll
    for (int i = 0; i < 4; ++i) {
        int id = t + i * 256; arow[i] = id >> 3; ac[i] = id & 7;
        aslot[i] = arow[i] * 64 + ((ac[i] ^ (arow[i] & 7)) * 8);
    }
    #pragma unroll
    for (int i = 0; i < 2; ++i) {
        int id = t + i * 256; brow[i] = id >> 3; bc[i] = id & 7;
        bslot[i] = brow[i] * 64 + ((bc[i] ^ (brow[i] & 7)) * 8);
    }

    uint4 ra[4], rb[2];
    #pragma unroll
    for (int i = 0; i < 4; ++i)
        ra[i] = *(const uint4*)(&A[(size_t)(mBase + arow[i]) * 512 + ac[i] * 8]);
    #pragma unroll
    for (int i = 0; i < 2; ++i)
        rb[i] = *(const uint4*)(&Wt[(size_t)(nBase + brow[i]) * 512 + bc[i] * 8]);

    f32x4 acc[4][2];
    #pragma unroll
    for (int i = 0; i < 4; ++i)
        #pragma unroll
        for (int j = 0; j < 2; ++j)
            acc[i][j] = (f32x4){0.f, 0.f, 0.f, 0.f};

    for (int kt = 0; kt < 8; ++kt) {
        __syncthreads();   // previous tile's frag reads complete
        #pragma unroll
        for (int i = 0; i < 4; ++i) *(uint4*)(&As[aslot[i]]) = ra[i];
        #pragma unroll
        for (int i = 0; i < 2; ++i) *(uint4*)(&Bs[bslot[i]]) = rb[i];
        __syncthreads();   // tile visible

        if (kt < 7) {      // prefetch next K-tile under the MFMAs
            const size_t kk = (size_t)(kt + 1) * 64;
            #pragma unroll
            for (int i = 0; i < 4; ++i)
                ra[i] = *(const uint4*)(&A[(size_t)(mBase + arow[i]) * 512 + kk + ac[i] * 8]);
            #pragma unroll
            for (int i = 0; i < 2; ++i)
                rb[i] = *(const uint4*)(&Wt[(size_t)(nBase + brow[i]) * 512 + kk + bc[i] * 8]);
        }

        #pragma unroll
        for (int kh = 0; kh < 2; ++kh) {
            const int cr = kh * 4 + qk;          // k-chunk 0..7
            bf16x8 bfr0, bfr1;
            {
                const int r0 = wn * 32 + rl;
                bfr0 = *(const bf16x8*)(&Bs[r0 * 64 + ((cr ^ (r0 & 7)) * 8)]);
                const int r1 = wn * 32 + 16 + rl;
                bfr1 = *(const bf16x8*)(&Bs[r1 * 64 + ((cr ^ (r1 & 7)) * 8)]);
            }
            #pragma unroll
            for (int fm = 0; fm < 4; ++fm) {
                const int rr = wm * 64 + fm * 16 + rl;
                bf16x8 afr = *(const bf16x8*)(&As[rr * 64 + ((cr ^ (rr & 7)) * 8)]);
                acc[fm][0] = __builtin_amdgcn_mfma_f32_16x16x32_bf16(afr, bfr0, acc[fm][0], 0, 0, 0);
                acc[fm][1] = __builtin_amdgcn_mfma_f32_16x16x32_bf16(afr, bfr1, acc[fm][1], 0, 0, 0);
            }
        }
    }

    // epilogue: bias + relu -> bf16; C/D: col = lane&15, row = (lane>>4)*4 + r
    #pragma unroll
    for (int fn = 0; fn < 2; ++fn) {
        const int col = nBase + wn * 32 + fn * 16 + rl;
        const float bias = b0[col];
        #pragma unroll
        for (int fm = 0; fm < 4; ++fm) {
            #pragma unroll
            for (int r = 0; r < 4; ++r) {
                const int row = mBase + wm * 64 + fm * 16 + (lane >> 4) * 4 + r;
                float v = acc[fm][fn][r] + bias;
                h[(size_t)row * 256 + col] = f2bf(v > 0.f ? v : 0.f);
            }
        }
    }
}

// ---------------------------------------------------------------------------
// Kernel 4 (unchanged): layer 1 + log_softmax, one block per output row,
// dot phase parallelized over 4 feature-quarters x 47 classes.
// ---------------------------------------------------------------------------
__global__ __launch_bounds__(256) void k_layer1(
    const unsigned short* __restrict__ h,  // [11264][256] bf16 bits
    const int* __restrict__ src1,
    const float* __restrict__ Ws1,    // [256][47]
    const float* __restrict__ Wn1,    // [256][47]
    const float* __restrict__ b1,     // [47]
    float* __restrict__ out)          // [1024][47]
{
    __shared__ float hd[256];
    __shared__ float mn[256];
    __shared__ float part[4][48];
    __shared__ float lg[CC];
    __shared__ float red[2];

    const int b = blockIdx.x;
    const int t = threadIdx.x;

    float acc = 0.f;
    const int* sp = src1 + b * FAN1;
    #pragma unroll
    for (int e = 0; e < FAN1; ++e)
        acc += bf2f(h[(size_t)sp[e] * 256 + t]);
    mn[t] = acc * (1.0f / (float)FAN1);
    hd[t] = bf2f(h[(size_t)b * 256 + t]);
    __syncthreads();

    const int p = t >> 6;       // feature quarter 0..3
    const int c = t & 63;       // class
    if (c < CC) {
        float s = 0.f;
        const int f0 = p * 64;
        #pragma unroll 8
        for (int f = f0; f < f0 + 64; ++f)
            s += hd[f] * Ws1[f * CC + c] + mn[f] * Wn1[f * CC + c];
        part[p][c] = s;
    }
    __syncthreads();

    if (t < CC)
        lg[t] = part[0][t] + part[1][t] + part[2][t] + part[3][t] + b1[t];
    __syncthreads();

    if (t == 0) {
        float m = -1e30f;
        for (int cc = 0; cc < CC; ++cc) m = fmaxf(m, lg[cc]);
        float se = 0.f;
        for (int cc = 0; cc < CC; ++cc) se += __expf(lg[cc] - m);
        red[0] = m;
        red[1] = logf(se);
    }
    __syncthreads();

    if (t < CC)
        out[(size_t)b * CC + t] = lg[t] - red[0] - red[1];
}

// ---------------------------------------------------------------------------
extern "C" void kernel_launch(void* const* d_in, const int* in_sizes, int n_in,
                              void* d_out, int out_size, void* d_ws, size_t ws_size,
                              hipStream_t stream)
{
    const float* x    = (const float*)d_in[0];
    const int*   src0 = (const int*)d_in[1];
    // d_in[2] = dst0 (structural: repeat(arange(N1),25)) -- unused
    const int*   src1 = (const int*)d_in[3];
    // d_in[4] = dst1 (structural: repeat(arange(B),10))  -- unused
    const float* Ws0  = (const float*)d_in[5];
    const float* Wn0  = (const float*)d_in[6];
    const float* b0   = (const float*)d_in[7];
    const float* Ws1  = (const float*)d_in[8];
    const float* Wn1  = (const float*)d_in[9];
    const float* b1   = (const float*)d_in[10];
    float* out = (float*)d_out;

    char* ws = (char*)d_ws;
    unsigned short* A  = (unsigned short*)ws;                       // 11264*512*2 = 11,534,336 B
    unsigned short* Wt = (unsigned short*)(ws + 11534336);          // 256*512*2   =    262,144 B
    unsigned short* h  = (unsigned short*)(ws + 11534336 + 262144); // 11264*256*2 =  5,767,168 B

    k_gather0<<<dim3(NN1 / 4), dim3(256), 0, stream>>>(x, src0, A);
    k_wconv  <<<dim3(256),     dim3(256), 0, stream>>>(Ws0, Wn0, Wt);
    k_gemm0  <<<dim3(NN1 / 128, FF1 / 64), dim3(256), 0, stream>>>(A, Wt, b0, h);
    k_layer1 <<<dim3(BB), dim3(256), 0, stream>>>(h, src1, Ws1, Wn1, b1, out);
}

// Round 7
// 70.363 us; speedup vs baseline: 1.3177x; 1.3177x over previous
//
#include <hip/hip_runtime.h>
#include <hip/hip_bf16.h>

// Problem constants (from reference)
#define NN0   292864
#define NN1   11264
#define BB    1024
#define FF0   256
#define FF1   256
#define CC    47
#define FAN0  25
#define FAN1  10

typedef __bf16 bf16x8 __attribute__((ext_vector_type(8)));
typedef float  f32x4  __attribute__((ext_vector_type(4)));

static __device__ __forceinline__ unsigned short f2bf(float f) {
    unsigned int u = __float_as_uint(f);
    u = u + 0x7fffu + ((u >> 16) & 1u);   // round-to-nearest-even
    return (unsigned short)(u >> 16);
}
static __device__ __forceinline__ float bf2f(unsigned short u) {
    return __uint_as_float(((unsigned int)u) << 16);
}

// ---------------------------------------------------------------------------
// Kernel 1: wconv (blocks 0..255, FRONT) + gather/mean (blocks 256..3071).
// Front placement: the 256 cheap wconv blocks dispatch first and drain while
// the BW-bound gather (the long pole) fills the machine -- saves one launch
// gap without delaying kernel completion (unlike R2's tail placement).
// Gather body is the round-3 verified form, verbatim.
// A[node][0:256]   = bf16(x[node])
// A[node][256:512] = bf16(mean_e x[src0[node*25+e]])
// Wt[n][k]         = bf16( k<256 ? Ws0[k][n] : Wn0[k-256][n] )
// ---------------------------------------------------------------------------
__global__ __launch_bounds__(256) void k_gather_w(
    const float* __restrict__ x, const int* __restrict__ src0,
    const float* __restrict__ Ws0, const float* __restrict__ Wn0,
    unsigned short* __restrict__ A, unsigned short* __restrict__ Wt)
{
    if (blockIdx.x < 256) {
        const int n = blockIdx.x;
        for (int k = threadIdx.x; k < 512; k += 256) {
            float v = (k < 256) ? Ws0[k * 256 + n] : Wn0[(k - 256) * 256 + n];
            Wt[n * 512 + k] = f2bf(v);
        }
        return;
    }

    const int wave = threadIdx.x >> 6;
    const int lane = threadIdx.x & 63;
    const int node = ((blockIdx.x - 256) << 2) + wave;   // 2816*4 = 11264 exact
    const float4* __restrict__ x4 = (const float4*)x;

    float4 s = x4[(size_t)node * 64 + lane];

    float ax = 0.f, ay = 0.f, az = 0.f, aw = 0.f;
    const int* sp = src0 + node * FAN0;
    #pragma unroll 5
    for (int e = 0; e < FAN0; ++e) {
        float4 v = x4[(size_t)sp[e] * 64 + lane];
        ax += v.x; ay += v.y; az += v.z; aw += v.w;
    }
    const float inv = 1.0f / (float)FAN0;

    ushort4 selfp, meanp;
    selfp.x = f2bf(s.x); selfp.y = f2bf(s.y); selfp.z = f2bf(s.z); selfp.w = f2bf(s.w);
    meanp.x = f2bf(ax * inv); meanp.y = f2bf(ay * inv);
    meanp.z = f2bf(az * inv); meanp.w = f2bf(aw * inv);

    const size_t base = (size_t)node * 512 + lane * 4;
    *(ushort4*)(&A[base])       = selfp;
    *(ushort4*)(&A[base + 256]) = meanp;
}

// ---------------------------------------------------------------------------
// Kernel 2 (round-3 form, verbatim): h = relu(A @ Wt^T + b0) -> bf16
// M=11264 N=256 K=512. Tile 128x64, BK=32, 4 waves (2x2), wave = 64x32.
// LDS rows padded 32->40 bf16 (2-way bank aliasing only = free).
// ---------------------------------------------------------------------------
__global__ __launch_bounds__(256) void k_gemm0(
    const unsigned short* __restrict__ A,   // [11264][512] bf16 bits
    const unsigned short* __restrict__ Wt,  // [256][512]   bf16 bits
    const float* __restrict__ b0,
    unsigned short* __restrict__ h)         // [11264][256] bf16 bits
{
    __shared__ unsigned short As[128 * 40];
    __shared__ unsigned short Bs[64 * 40];

    const int t     = threadIdx.x;
    const int mBase = blockIdx.x * 128;
    const int nBase = blockIdx.y * 64;
    const int lane  = t & 63;
    const int wave  = t >> 6;
    const int wm    = wave >> 1;     // 0..1 : which 64-row half
    const int wn    = wave & 1;      // 0..1 : which 32-col half

    const int ar  = t >> 2;          // 0..63
    const int akc = t & 3;           // 0..3 (which 8-bf16 chunk in the 32-wide row)

    uint4 ra0, ra1, rb;
    const size_t aoff0 = (size_t)(mBase + ar) * 512 + akc * 8;
    const size_t aoff1 = (size_t)(mBase + 64 + ar) * 512 + akc * 8;
    const size_t boff  = (size_t)(nBase + ar) * 512 + akc * 8;

    f32x4 acc[4][2];
    #pragma unroll
    for (int i = 0; i < 4; ++i)
        #pragma unroll
        for (int j = 0; j < 2; ++j)
            acc[i][j] = (f32x4){0.f, 0.f, 0.f, 0.f};

    ra0 = *(const uint4*)(&A[aoff0]);
    ra1 = *(const uint4*)(&A[aoff1]);
    rb  = *(const uint4*)(&Wt[boff]);

    const int k8 = (lane >> 4) * 8;
    const int rl = lane & 15;

    for (int ki = 0; ki < 16; ++ki) {
        __syncthreads();   // previous iter's frag reads done
        *(uint4*)(&As[ar * 40 + akc * 8])        = ra0;
        *(uint4*)(&As[(64 + ar) * 40 + akc * 8]) = ra1;
        *(uint4*)(&Bs[ar * 40 + akc * 8])        = rb;
        __syncthreads();   // tile visible

        if (ki < 15) {     // prefetch next k-step under the MFMAs
            const size_t kk = (size_t)(ki + 1) * 32;
            ra0 = *(const uint4*)(&A[aoff0 + kk]);
            ra1 = *(const uint4*)(&A[aoff1 + kk]);
            rb  = *(const uint4*)(&Wt[boff + kk]);
        }

        bf16x8 bfr0 = *(const bf16x8*)(&Bs[(wn * 32 + rl) * 40 + k8]);
        bf16x8 bfr1 = *(const bf16x8*)(&Bs[(wn * 32 + 16 + rl) * 40 + k8]);
        #pragma unroll
        for (int fm = 0; fm < 4; ++fm) {
            bf16x8 afr = *(const bf16x8*)(&As[(wm * 64 + fm * 16 + rl) * 40 + k8]);
            acc[fm][0] = __builtin_amdgcn_mfma_f32_16x16x32_bf16(afr, bfr0, acc[fm][0], 0, 0, 0);
            acc[fm][1] = __builtin_amdgcn_mfma_f32_16x16x32_bf16(afr, bfr1, acc[fm][1], 0, 0, 0);
        }
    }

    // epilogue: bias + relu -> bf16; C/D: col = lane&15, row = (lane>>4)*4 + r
    #pragma unroll
    for (int fn = 0; fn < 2; ++fn) {
        const int col = nBase + wn * 32 + fn * 16 + rl;
        const float bias = b0[col];
        #pragma unroll
        for (int fm = 0; fm < 4; ++fm) {
            #pragma unroll
            for (int r = 0; r < 4; ++r) {
                const int row = mBase + wm * 64 + fm * 16 + (lane >> 4) * 4 + r;
                float v = acc[fm][fn][r] + bias;
                h[(size_t)row * 256 + col] = f2bf(v > 0.f ? v : 0.f);
            }
        }
    }
}

// ---------------------------------------------------------------------------
// Kernel 3 (unchanged): layer 1 + log_softmax, one block per output row,
// dot phase parallelized over 4 feature-quarters x 47 classes.
// ---------------------------------------------------------------------------
__global__ __launch_bounds__(256) void k_layer1(
    const unsigned short* __restrict__ h,  // [11264][256] bf16 bits
    const int* __restrict__ src1,
    const float* __restrict__ Ws1,    // [256][47]
    const float* __restrict__ Wn1,    // [256][47]
    const float* __restrict__ b1,     // [47]
    float* __restrict__ out)          // [1024][47]
{
    __shared__ float hd[256];
    __shared__ float mn[256];
    __shared__ float part[4][48];
    __shared__ float lg[CC];
    __shared__ float red[2];

    const int b = blockIdx.x;
    const int t = threadIdx.x;

    float acc = 0.f;
    const int* sp = src1 + b * FAN1;
    #pragma unroll
    for (int e = 0; e < FAN1; ++e)
        acc += bf2f(h[(size_t)sp[e] * 256 + t]);
    mn[t] = acc * (1.0f / (float)FAN1);
    hd[t] = bf2f(h[(size_t)b * 256 + t]);
    __syncthreads();

    const int p = t >> 6;       // feature quarter 0..3
    const int c = t & 63;       // class
    if (c < CC) {
        float s = 0.f;
        const int f0 = p * 64;
        #pragma unroll 8
        for (int f = f0; f < f0 + 64; ++f)
            s += hd[f] * Ws1[f * CC + c] + mn[f] * Wn1[f * CC + c];
        part[p][c] = s;
    }
    __syncthreads();

    if (t < CC)
        lg[t] = part[0][t] + part[1][t] + part[2][t] + part[3][t] + b1[t];
    __syncthreads();

    if (t == 0) {
        float m = -1e30f;
        for (int cc = 0; cc < CC; ++cc) m = fmaxf(m, lg[cc]);
        float se = 0.f;
        for (int cc = 0; cc < CC; ++cc) se += __expf(lg[cc] - m);
        red[0] = m;
        red[1] = logf(se);
    }
    __syncthreads();

    if (t < CC)
        out[(size_t)b * CC + t] = lg[t] - red[0] - red[1];
}

// ---------------------------------------------------------------------------
extern "C" void kernel_launch(void* const* d_in, const int* in_sizes, int n_in,
                              void* d_out, int out_size, void* d_ws, size_t ws_size,
                              hipStream_t stream)
{
    const float* x    = (const float*)d_in[0];
    const int*   src0 = (const int*)d_in[1];
    // d_in[2] = dst0 (structural: repeat(arange(N1),25)) -- unused
    const int*   src1 = (const int*)d_in[3];
    // d_in[4] = dst1 (structural: repeat(arange(B),10))  -- unused
    const float* Ws0  = (const float*)d_in[5];
    const float* Wn0  = (const float*)d_in[6];
    const float* b0   = (const float*)d_in[7];
    const float* Ws1  = (const float*)d_in[8];
    const float* Wn1  = (const float*)d_in[9];
    const float* b1   = (const float*)d_in[10];
    float* out = (float*)d_out;

    char* ws = (char*)d_ws;
    unsigned short* A  = (unsigned short*)ws;                       // 11264*512*2 = 11,534,336 B
    unsigned short* Wt = (unsigned short*)(ws + 11534336);          // 256*512*2   =    262,144 B
    unsigned short* h  = (unsigned short*)(ws + 11534336 + 262144); // 11264*256*2 =  5,767,168 B

    k_gather_w<<<dim3(256 + NN1 / 4), dim3(256), 0, stream>>>(x, src0, Ws0, Wn0, A, Wt);
    k_gemm0   <<<dim3(NN1 / 128, FF1 / 64), dim3(256), 0, stream>>>(A, Wt, b0, h);
    k_layer1  <<<dim3(BB), dim3(256), 0, stream>>>(h, src1, Ws1, Wn1, b1, out);
}